// Round 1
// baseline (114.662 us; speedup 1.0000x reference)
//
#include <hip/hip_runtime.h>
#include <math.h>

#define BB 4
#define S 8192
#define C 256
#define NW 2048
#define WS 256
#define PSZ 256
#define DD 32
#define KK 65
#define TOTW (BB * NW) /* 8192 */

// ---------------------------------------------------------------------------
// Kernel 0: transpose W_p [PSZ][WS] -> WpT [WS][PSZ] so the GEMM kernel can
// read weight rows coalesced (lane = output column p).
// ---------------------------------------------------------------------------
__global__ __launch_bounds__(256) void wp_transpose(const float* __restrict__ Wp,
                                                    float* __restrict__ WpT) {
    int p = blockIdx.x;        // 256 blocks
    int ws = threadIdx.x;      // 256 threads
    WpT[ws * PSZ + p] = Wp[p * WS + ws];
}

// ---------------------------------------------------------------------------
// Kernel 1: per-window precompute.
//   g[w][c]  = sum_ws c_t[w][ws] * W_a[ws][c]          (fold of W_a into c_t)
//   p_t[w]   = S * sigmoid( sum_p tanh(h[w][p]) * V_p[p] ),
//   h[w][p]  = sum_ws c_t[w][ws] * W_p[p][ws]
// 16 windows per block, 256 threads. Thread t owns output column t for both
// matmuls; weight rows are read coalesced (WpT / W_a are [ws][col]).
// ---------------------------------------------------------------------------
__global__ __launch_bounds__(256) void precomp(const float* __restrict__ ct,
                                               const float* __restrict__ WpT,
                                               const float* __restrict__ Wa,
                                               const float* __restrict__ Vp,
                                               float* __restrict__ g,
                                               float* __restrict__ pt) {
    __shared__ __align__(16) float ctl[16][WS];   // 16 KB
    __shared__ float red[16][4];

    const int tid = threadIdx.x;
    const int wbase = blockIdx.x * 16;

    // cooperative coalesced load of 16 c_t rows (c_t is [B*NW][WS] flat)
    {
        const float4* src = (const float4*)(ct + (size_t)wbase * WS);
        float4* dst = (float4*)(&ctl[0][0]);
#pragma unroll
        for (int i = 0; i < 4; i++) dst[tid + i * 256] = src[tid + i * 256];
    }
    __syncthreads();

    float hacc[16], gacc[16];
#pragma unroll
    for (int r = 0; r < 16; r++) { hacc[r] = 0.f; gacc[r] = 0.f; }

    for (int ws = 0; ws < WS; ws += 4) {
        const float wp0 = WpT[(ws + 0) * PSZ + tid];
        const float wp1 = WpT[(ws + 1) * PSZ + tid];
        const float wp2 = WpT[(ws + 2) * PSZ + tid];
        const float wp3 = WpT[(ws + 3) * PSZ + tid];
        const float wa0 = Wa[(ws + 0) * C + tid];
        const float wa1 = Wa[(ws + 1) * C + tid];
        const float wa2 = Wa[(ws + 2) * C + tid];
        const float wa3 = Wa[(ws + 3) * C + tid];
#pragma unroll
        for (int r = 0; r < 16; r++) {
            const float4 c4 = *(const float4*)&ctl[r][ws];   // LDS broadcast
            hacc[r] = fmaf(c4.x, wp0, hacc[r]);
            hacc[r] = fmaf(c4.y, wp1, hacc[r]);
            hacc[r] = fmaf(c4.z, wp2, hacc[r]);
            hacc[r] = fmaf(c4.w, wp3, hacc[r]);
            gacc[r] = fmaf(c4.x, wa0, gacc[r]);
            gacc[r] = fmaf(c4.y, wa1, gacc[r]);
            gacc[r] = fmaf(c4.z, wa2, gacc[r]);
            gacc[r] = fmaf(c4.w, wa3, gacc[r]);
        }
    }

    // write g rows (coalesced)
#pragma unroll
    for (int r = 0; r < 16; r++) g[(size_t)(wbase + r) * C + tid] = gacc[r];

    // p_t: reduce tanh(h)*V_p over the 256 columns
    const int lane = tid & 63, wv = tid >> 6;
    const float vp = Vp[tid];
#pragma unroll
    for (int r = 0; r < 16; r++) {
        float v = tanhf(hacc[r]) * vp;
#pragma unroll
        for (int off = 32; off >= 1; off >>= 1) v += __shfl_xor(v, off);
        if (lane == 0) red[r][wv] = v;
    }
    __syncthreads();
    if (tid < 16) {
        const float x = red[tid][0] + red[tid][1] + red[tid][2] + red[tid][3];
        const float sig = 1.f / (1.f + expf(-x));
        pt[wbase + tid] = (float)S * sig;
    }
}

// ---------------------------------------------------------------------------
// Kernel 2: gather-attention, one window per block (8192 blocks, 256 thr).
// Online softmax over the 65 keys; each q-row read ONCE (num/den/max online).
// Key k is wave-uniform; lane holds 4 channels (float4). Score = wave-wide
// shuffle reduction. Gaussian factor folded into the numerator only
// (reference: prob = softmax(a) * gauss; denominator has NO gauss).
// ---------------------------------------------------------------------------
__global__ __launch_bounds__(256) void attn(const float* __restrict__ q,
                                            const float* __restrict__ g,
                                            const float* __restrict__ pt,
                                            float* __restrict__ out) {
    const int wg = blockIdx.x;                 // global window
    const int b = wg >> 11;                    // NW = 2048
    const int tid = threadIdx.x, lane = tid & 63, wv = tid >> 6;

    const float p = pt[wg];
    const int s0 = (int)p;                     // trunc == floor (p > 0)

    const float4 gv = ((const float4*)(g + (size_t)wg * C))[lane];
    const float* qb = q + (size_t)b * S * C;

    float m = -INFINITY, den = 0.f;
    float nx = 0.f, ny = 0.f, nz = 0.f, nw_ = 0.f;

    for (int k = wv; k < KK; k += 4) {
        const int s = s0 + (k - DD);
        if ((unsigned)s < (unsigned)S) {       // valid key (else -inf / zeroed)
            const float4 qv = ((const float4*)(qb + (size_t)s * C))[lane];
            float d = qv.x * gv.x + qv.y * gv.y + qv.z * gv.z + qv.w * gv.w;
#pragma unroll
            for (int off = 32; off >= 1; off >>= 1) d += __shfl_xor(d, off);
            const float dsf = (float)s - p;
            const float gauss = expf(dsf * dsf * (-2.f / 1024.f));  // D*D=1024
            if (d > m) {
                const float sc = expf(m - d);  // expf(-inf)=0 on first key
                den = den * sc + 1.f;
                nx = nx * sc + gauss * qv.x;
                ny = ny * sc + gauss * qv.y;
                nz = nz * sc + gauss * qv.z;
                nw_ = nw_ * sc + gauss * qv.w;
                m = d;
            } else {
                const float e = expf(d - m);
                den += e;
                const float eg = e * gauss;
                nx = fmaf(eg, qv.x, nx);
                ny = fmaf(eg, qv.y, ny);
                nz = fmaf(eg, qv.z, nz);
                nw_ = fmaf(eg, qv.w, nw_);
            }
        }
    }

    // merge the 4 per-wave partial (m, den, num[]) states
    __shared__ float mw[4], dw[4];
    __shared__ __align__(16) float nwl[4][C];
    ((float4*)&nwl[wv][0])[lane] = make_float4(nx, ny, nz, nw_);
    if (lane == 0) { mw[wv] = m; dw[wv] = den; }
    __syncthreads();

    const float M = fmaxf(fmaxf(mw[0], mw[1]), fmaxf(mw[2], mw[3]));
    float dtot = 0.f, ntot = 0.f;
#pragma unroll
    for (int w = 0; w < 4; w++) {
        const float mwv = mw[w];
        if (mwv > -INFINITY) {                 // skip waves with no valid key
            const float sc = expf(mwv - M);
            dtot = fmaf(dw[w], sc, dtot);
            ntot = fmaf(nwl[w][tid], sc, ntot);
        }
    }
    out[(size_t)wg * C + tid] = ntot / dtot;
}

// ---------------------------------------------------------------------------
extern "C" void kernel_launch(void* const* d_in, const int* in_sizes, int n_in,
                              void* d_out, int out_size, void* d_ws, size_t ws_size,
                              hipStream_t stream) {
    const float* q  = (const float*)d_in[0];
    const float* ct = (const float*)d_in[1];
    const float* Wa = (const float*)d_in[2];
    const float* Wp = (const float*)d_in[3];
    const float* Vp = (const float*)d_in[4];
    float* out = (float*)d_out;

    char* ws = (char*)d_ws;
    float* WpT = (float*)ws;                          // 256 KB
    float* pt  = (float*)(ws + 262144);               // 32 KB
    float* g   = (float*)(ws + 262144 + 32768);       // 8 MB
    // total workspace use: 8,683,520 bytes

    wp_transpose<<<PSZ, WS, 0, stream>>>(Wp, WpT);
    precomp<<<TOTW / 16, 256, 0, stream>>>(ct, WpT, Wa, Vp, g, pt);
    attn<<<TOTW, 256, 0, stream>>>(q, g, pt, out);
}

// Round 2
// 107.963 us; speedup vs baseline: 1.0620x; 1.0620x over previous
//
#include <hip/hip_runtime.h>
#include <math.h>

#define BB 4
#define S 8192
#define C 256
#define NW 2048
#define WS 256
#define PSZ 256
#define DD 32
#define KK 65
#define TOTW (BB * NW) /* 8192 */

// ---------------------------------------------------------------------------
// Kernel 0: transpose W_p [PSZ][WS] -> WpT [WS][PSZ]
// ---------------------------------------------------------------------------
__global__ __launch_bounds__(256) void wp_transpose(const float* __restrict__ Wp,
                                                    float* __restrict__ WpT) {
    int p = blockIdx.x;
    int ws = threadIdx.x;
    WpT[ws * PSZ + p] = Wp[p * WS + ws];
}

// ---------------------------------------------------------------------------
// Kernel 1: per-window precompute (unchanged this round).
//   g[w][c] = sum_ws c_t[w][ws] * W_a[ws][c]
//   p_t[w]  = S * sigmoid( sum_p tanh(c_t @ W_p^T)[p] * V_p[p] )
// ---------------------------------------------------------------------------
__global__ __launch_bounds__(256) void precomp(const float* __restrict__ ct,
                                               const float* __restrict__ WpT,
                                               const float* __restrict__ Wa,
                                               const float* __restrict__ Vp,
                                               float* __restrict__ g,
                                               float* __restrict__ pt) {
    __shared__ __align__(16) float ctl[16][WS];
    __shared__ float red[16][4];

    const int tid = threadIdx.x;
    const int wbase = blockIdx.x * 16;

    {
        const float4* src = (const float4*)(ct + (size_t)wbase * WS);
        float4* dst = (float4*)(&ctl[0][0]);
#pragma unroll
        for (int i = 0; i < 4; i++) dst[tid + i * 256] = src[tid + i * 256];
    }
    __syncthreads();

    float hacc[16], gacc[16];
#pragma unroll
    for (int r = 0; r < 16; r++) { hacc[r] = 0.f; gacc[r] = 0.f; }

    for (int ws = 0; ws < WS; ws += 4) {
        const float wp0 = WpT[(ws + 0) * PSZ + tid];
        const float wp1 = WpT[(ws + 1) * PSZ + tid];
        const float wp2 = WpT[(ws + 2) * PSZ + tid];
        const float wp3 = WpT[(ws + 3) * PSZ + tid];
        const float wa0 = Wa[(ws + 0) * C + tid];
        const float wa1 = Wa[(ws + 1) * C + tid];
        const float wa2 = Wa[(ws + 2) * C + tid];
        const float wa3 = Wa[(ws + 3) * C + tid];
#pragma unroll
        for (int r = 0; r < 16; r++) {
            const float4 c4 = *(const float4*)&ctl[r][ws];
            hacc[r] = fmaf(c4.x, wp0, hacc[r]);
            hacc[r] = fmaf(c4.y, wp1, hacc[r]);
            hacc[r] = fmaf(c4.z, wp2, hacc[r]);
            hacc[r] = fmaf(c4.w, wp3, hacc[r]);
            gacc[r] = fmaf(c4.x, wa0, gacc[r]);
            gacc[r] = fmaf(c4.y, wa1, gacc[r]);
            gacc[r] = fmaf(c4.z, wa2, gacc[r]);
            gacc[r] = fmaf(c4.w, wa3, gacc[r]);
        }
    }

#pragma unroll
    for (int r = 0; r < 16; r++) g[(size_t)(wbase + r) * C + tid] = gacc[r];

    const int lane = tid & 63, wv = tid >> 6;
    const float vp = Vp[tid];
#pragma unroll
    for (int r = 0; r < 16; r++) {
        float v = tanhf(hacc[r]) * vp;
#pragma unroll
        for (int off = 32; off >= 1; off >>= 1) v += __shfl_xor(v, off);
        if (lane == 0) red[r][wv] = v;
    }
    __syncthreads();
    if (tid < 16) {
        const float x = red[tid][0] + red[tid][1] + red[tid][2] + red[tid][3];
        const float sig = 1.f / (1.f + expf(-x));
        pt[wbase + tid] = (float)S * sig;
    }
}

// ---------------------------------------------------------------------------
// Kernel 2: gather-attention, ONE WAVE PER WINDOW (2048 blocks x 256 thr =
// 4 windows/block). Wave split into 4 groups of 16 lanes; each iteration
// processes 4 keys (one per group). Lane covers 16 channels as 4 float4
// slots at c = j*64 + sub*4 (j=0..3, sub=lane&15) -> every load instr is a
// 256B-contiguous chunk per group. Score reduce = 4 shuffles over 16 lanes.
// Branchless online softmax: OOB keys get score -3e38 (exp -> exactly 0),
// row index clamped so the load stays in-bounds. Gaussian folded into the
// numerator exponent (reference multiplies softmax output by gauss, so the
// denominator uses the plain exp). Final 4-group merge via register
// butterfly (shfl_xor 16/32) — no LDS, no __syncthreads.
// ---------------------------------------------------------------------------
__global__ __launch_bounds__(256) void attn(const float* __restrict__ q,
                                            const float* __restrict__ g,
                                            const float* __restrict__ pt,
                                            float* __restrict__ out) {
    const int tid = threadIdx.x;
    const int lane = tid & 63;
    const int wv = tid >> 6;
    const int wg = (blockIdx.x << 2) | wv;     // global window
    const int b = wg >> 11;                    // NW = 2048
    const int grp = lane >> 4;                 // key sub-slot
    const int sub = lane & 15;                 // channel group

    const float p = pt[wg];
    const int s0 = (int)p;                     // trunc == floor (p > 0)

    const float* grow = g + (size_t)wg * C + sub * 4;
    const float4 g0 = *(const float4*)(grow);
    const float4 g1 = *(const float4*)(grow + 64);
    const float4 g2 = *(const float4*)(grow + 128);
    const float4 g3 = *(const float4*)(grow + 192);

    const float* qb = q + (size_t)b * S * C + sub * 4;

    float m = -1e30f, den = 0.f;
    float4 a0 = {0, 0, 0, 0}, a1 = {0, 0, 0, 0}, a2 = {0, 0, 0, 0}, a3 = {0, 0, 0, 0};

    for (int it = 0; it < 17; it++) {
        const int k = it * 4 + grp;
        const int s = s0 + k - DD;
        const bool valid = (k <= 64) && ((unsigned)s < (unsigned)S);
        const int srow = min(max(s, 0), S - 1);

        const float* qr = qb + (size_t)srow * C;
        const float4 q0 = *(const float4*)(qr);
        const float4 q1 = *(const float4*)(qr + 64);
        const float4 q2 = *(const float4*)(qr + 128);
        const float4 q3 = *(const float4*)(qr + 192);

        float d = q0.x * g0.x;
        d = fmaf(q0.y, g0.y, d); d = fmaf(q0.z, g0.z, d); d = fmaf(q0.w, g0.w, d);
        d = fmaf(q1.x, g1.x, d); d = fmaf(q1.y, g1.y, d);
        d = fmaf(q1.z, g1.z, d); d = fmaf(q1.w, g1.w, d);
        d = fmaf(q2.x, g2.x, d); d = fmaf(q2.y, g2.y, d);
        d = fmaf(q2.z, g2.z, d); d = fmaf(q2.w, g2.w, d);
        d = fmaf(q3.x, g3.x, d); d = fmaf(q3.y, g3.y, d);
        d = fmaf(q3.z, g3.z, d); d = fmaf(q3.w, g3.w, d);
#pragma unroll
        for (int off = 8; off >= 1; off >>= 1) d += __shfl_xor(d, off);

        d = valid ? d : -3e38f;

        const float fs = (float)s - p;
        const float t = fs * (1.f / (float)DD);
        const float lg = -2.f * t * t;

        const float mn = fmaxf(m, d);
        const float sc = __expf(m - mn);       // rescale old state
        const float e  = __expf(d - mn);       // denominator term
        const float eg = __expf(d - mn + lg);  // numerator term (exp * gauss)
        den = fmaf(den, sc, e);
        m = mn;

        a0.x = fmaf(eg, q0.x, a0.x * sc); a0.y = fmaf(eg, q0.y, a0.y * sc);
        a0.z = fmaf(eg, q0.z, a0.z * sc); a0.w = fmaf(eg, q0.w, a0.w * sc);
        a1.x = fmaf(eg, q1.x, a1.x * sc); a1.y = fmaf(eg, q1.y, a1.y * sc);
        a1.z = fmaf(eg, q1.z, a1.z * sc); a1.w = fmaf(eg, q1.w, a1.w * sc);
        a2.x = fmaf(eg, q2.x, a2.x * sc); a2.y = fmaf(eg, q2.y, a2.y * sc);
        a2.z = fmaf(eg, q2.z, a2.z * sc); a2.w = fmaf(eg, q2.w, a2.w * sc);
        a3.x = fmaf(eg, q3.x, a3.x * sc); a3.y = fmaf(eg, q3.y, a3.y * sc);
        a3.z = fmaf(eg, q3.z, a3.z * sc); a3.w = fmaf(eg, q3.w, a3.w * sc);
    }

    // merge the 4 groups (cross-lane butterfly; m/den uniform within group)
    float M = m;
    M = fmaxf(M, __shfl_xor(M, 16));
    M = fmaxf(M, __shfl_xor(M, 32));
    const float scg = __expf(m - M);

    den *= scg;
    den += __shfl_xor(den, 16);
    den += __shfl_xor(den, 32);

#define MERGE(v) { v *= scg; v += __shfl_xor(v, 16); v += __shfl_xor(v, 32); }
    MERGE(a0.x) MERGE(a0.y) MERGE(a0.z) MERGE(a0.w)
    MERGE(a1.x) MERGE(a1.y) MERGE(a1.z) MERGE(a1.w)
    MERGE(a2.x) MERGE(a2.y) MERGE(a2.z) MERGE(a2.w)
    MERGE(a3.x) MERGE(a3.y) MERGE(a3.z) MERGE(a3.w)
#undef MERGE

    // every lane now holds the totals for its channel slots; lane writes the
    // float4 belonging to its own group -> one fully-coalesced 1KB store/wave
    float4 o = a0;
    if (grp == 1) o = a1;
    else if (grp == 2) o = a2;
    else if (grp == 3) o = a3;

    const float r = 1.f / den;
    o.x *= r; o.y *= r; o.z *= r; o.w *= r;

    *(float4*)(out + (size_t)wg * C + lane * 4) = o;
}

// ---------------------------------------------------------------------------
extern "C" void kernel_launch(void* const* d_in, const int* in_sizes, int n_in,
                              void* d_out, int out_size, void* d_ws, size_t ws_size,
                              hipStream_t stream) {
    const float* q  = (const float*)d_in[0];
    const float* ct = (const float*)d_in[1];
    const float* Wa = (const float*)d_in[2];
    const float* Wp = (const float*)d_in[3];
    const float* Vp = (const float*)d_in[4];
    float* out = (float*)d_out;

    char* ws = (char*)d_ws;
    float* WpT = (float*)ws;                          // 256 KB
    float* pt  = (float*)(ws + 262144);               // 32 KB
    float* g   = (float*)(ws + 262144 + 32768);       // 8 MB

    wp_transpose<<<PSZ, WS, 0, stream>>>(Wp, WpT);
    precomp<<<TOTW / 16, 256, 0, stream>>>(ct, WpT, Wa, Vp, g, pt);
    attn<<<TOTW / 4, 256, 0, stream>>>(q, g, pt, out);
}